// Round 7
// baseline (763.760 us; speedup 1.0000x reference)
//
#include <hip/hip_runtime.h>

#define NN 50000
#define EE 800000
#define DD 128
#define CC 16

// ---------------- degree counting (int) ----------------
__global__ void k_degcount(const int* __restrict__ src, const int* __restrict__ dst,
                           int* __restrict__ cs, int* __restrict__ cd) {
    int e = blockIdx.x * blockDim.x + threadIdx.x;
    if (e < EE) {
        atomicAdd(&cs[src[e]], 1);
        atomicAdd(&cd[dst[e]], 1);
    }
}

__global__ void k_degfinalize(const int* __restrict__ cs, const int* __restrict__ cd,
                              float* __restrict__ iso, float* __restrict__ isi) {
    int i = blockIdx.x * blockDim.x + threadIdx.x;
    if (i < NN) {
        iso[i] = rsqrtf(fmaxf((float)cs[i], 1.0f));
        isi[i] = rsqrtf(fmaxf((float)cd[i], 1.0f));
    }
}

// ---------------- hierarchical exclusive scan: cd -> rowptr ----------------
#define SBLK 256
#define NBLK_SCAN ((NN + SBLK - 1) / SBLK)   // 196

__global__ __launch_bounds__(SBLK) void k_blocksum(const int* __restrict__ cnt,
                                                   int* __restrict__ partial) {
    __shared__ int s[SBLK];
    int t = threadIdx.x;
    int i = blockIdx.x * SBLK + t;
    int v = (i < NN) ? cnt[i] : 0;
    s[t] = v;
    __syncthreads();
    for (int off = SBLK / 2; off > 0; off >>= 1) {
        if (t < off) s[t] += s[t + off];
        __syncthreads();
    }
    if (t == 0) partial[blockIdx.x] = s[0];
}

__global__ __launch_bounds__(SBLK) void k_scanpartial(const int* __restrict__ partial,
                                                      int* __restrict__ pp,
                                                      int* __restrict__ rowptr) {
    __shared__ int s[SBLK];
    int t = threadIdx.x;
    int v = (t < NBLK_SCAN) ? partial[t] : 0;
    s[t] = v;
    __syncthreads();
    for (int off = 1; off < SBLK; off <<= 1) {
        int x = (t >= off) ? s[t - off] : 0;
        __syncthreads();
        s[t] += x;
        __syncthreads();
    }
    if (t < NBLK_SCAN) pp[t] = s[t] - v;   // exclusive prefix of block partials
    if (t == SBLK - 1) rowptr[NN] = s[t];  // grand total (== EE)
}

__global__ __launch_bounds__(SBLK) void k_writerowptr(const int* __restrict__ cnt,
                                                      const int* __restrict__ pp,
                                                      int* __restrict__ rowptr) {
    __shared__ int s[SBLK];
    int t = threadIdx.x;
    int i = blockIdx.x * SBLK + t;
    int v = (i < NN) ? cnt[i] : 0;
    s[t] = v;
    __syncthreads();
    for (int off = 1; off < SBLK; off <<= 1) {
        int x = (t >= off) ? s[t - off] : 0;
        __syncthreads();
        s[t] += x;
        __syncthreads();
    }
    if (i < NN) rowptr[i] = pp[blockIdx.x] + s[t] - v;
}

// ---------------- CSR fill with folded edge weight (guarded store) ----------------
__global__ void k_fill(const int* __restrict__ src, const int* __restrict__ dst,
                       const float* __restrict__ ew, const float* __restrict__ iso,
                       const float* __restrict__ isi, const int* __restrict__ rowptr,
                       int* __restrict__ cursor, int2* __restrict__ pairs) {
    int e = blockIdx.x * blockDim.x + threadIdx.x;
    if (e < EE) {
        int d = dst[e];
        int s = src[e];
        int pos = atomicAdd(&cursor[d], 1);
        float w = ew[e] * iso[s] * isi[d];
        int2 p;
        p.x = s;
        p.y = __float_as_int(w);
        int idx = rowptr[d] + pos;
        if ((unsigned)idx < EE) pairs[idx] = p;   // defensive: never store wild
    }
}

// ---------------- CSR gather (proven round-6 version, clamped) ----------------
// 1 wave / node, float2 per lane; 2 edges per iteration.
__global__ __launch_bounds__(256) void k_gather(
        const float* __restrict__ X, const int* __restrict__ rowptr,
        const int2* __restrict__ pairs, float* __restrict__ G) {
    int node = blockIdx.x * 4 + (threadIdx.x >> 6);
    if (node >= NN) return;
    int lane = threadIdx.x & 63;
    int c = lane * 2;
    int j = rowptr[node];
    int end = rowptr[node + 1];
    // defensive clamps: these values come from workspace memory
    j = max(0, min(j, EE));
    end = max(j, min(end, EE));
    float2 acc = make_float2(0.f, 0.f);
    for (; j + 1 < end; j += 2) {
        int2 p0 = pairs[j];
        int2 p1 = pairs[j + 1];
        int c0 = ((unsigned)p0.x < NN) ? p0.x : 0;
        int c1 = ((unsigned)p1.x < NN) ? p1.x : 0;
        float w0 = __int_as_float(p0.y);
        float w1 = __int_as_float(p1.y);
        float2 h0 = *(const float2*)&X[c0 * DD + c];
        float2 h1 = *(const float2*)&X[c1 * DD + c];
        acc.x = fmaf(h0.x, w0, acc.x);
        acc.y = fmaf(h0.y, w0, acc.y);
        acc.x = fmaf(h1.x, w1, acc.x);
        acc.y = fmaf(h1.y, w1, acc.y);
    }
    if (j < end) {
        int2 p0 = pairs[j];
        int c0 = ((unsigned)p0.x < NN) ? p0.x : 0;
        float w0 = __int_as_float(p0.y);
        float2 h0 = *(const float2*)&X[c0 * DD + c];
        acc.x = fmaf(h0.x, w0, acc.x);
        acc.y = fmaf(h0.y, w0, acc.y);
    }
    *(float2*)&G[node * DD + c] = acc;
}

// ---------------- 128x128 GEMM v2: X-tile resident (swizzled), W streamed ----------------
// Y[64rows, 128] per block = Xs[64,128] @ W[128,128] + bias (+RES) (relu?)
// LDS: Xs 32 KB (float4-slot XOR swizzle) + Wc 16 KB k-chunk = 48 KB.
// Thread: 8 rows x 4 cols. FMA-bound: 8192 FMA-cyc vs ~4608 LDS-cyc per wave.
#define GTILE 64
__global__ __launch_bounds__(256) void k_gemm128(
        const float* __restrict__ X, const float* __restrict__ W,
        const float* __restrict__ bias, const float* __restrict__ RES,
        float* __restrict__ Y, int M, int relu) {
    __shared__ float Xs[GTILE * 128];   // float4 slots: [row][c4 ^ ((row>>3)&7)]
    __shared__ float Wc[32 * 128];      // k-chunk, row-major [k][c]
    const int t = threadIdx.x;
    const int row0 = blockIdx.x * GTILE;

    float4* Xs4 = (float4*)Xs;
    float4* Wc4 = (float4*)Wc;
    const float4* X4 = (const float4*)X;
    const float4* W4 = (const float4*)W;

    // stage 64 rows of X with swizzle (8 float4 per thread, coalesced reads)
    for (int i = t; i < GTILE * 32; i += 256) {
        int r = i >> 5;
        int c4 = i & 31;
        int gr = row0 + r;
        float4 v = make_float4(0.f, 0.f, 0.f, 0.f);
        if (gr < M) v = X4[(long long)gr * 32 + c4];
        int slot = c4 ^ ((r >> 3) & 7);
        Xs4[r * 32 + slot] = v;
    }

    const int sc4 = t & 31;            // output col group (float4 index)
    const int r0 = (t >> 5) * 8;       // 8 rows per thread

    float4 acc[8];
#pragma unroll
    for (int r = 0; r < 8; ++r) acc[r] = make_float4(0.f, 0.f, 0.f, 0.f);

    for (int kc = 0; kc < 4; ++kc) {
        __syncthreads();
        // stage W rows [kc*32, kc*32+32)
        for (int i = t; i < 32 * 32; i += 256) {
            int k = i >> 5;
            int c4 = i & 31;
            Wc4[k * 32 + c4] = W4[(long long)(kc * 32 + k) * 32 + c4];
        }
        __syncthreads();

#pragma unroll
        for (int k = 0; k < 32; k += 4) {
            float4 w0 = Wc4[(k + 0) * 32 + sc4];
            float4 w1 = Wc4[(k + 1) * 32 + sc4];
            float4 w2 = Wc4[(k + 2) * 32 + sc4];
            float4 w3 = Wc4[(k + 3) * 32 + sc4];
            int kf4 = kc * 8 + (k >> 2);
#pragma unroll
            for (int r = 0; r < 8; ++r) {
                int row = r0 + r;
                float4 xv = Xs4[row * 32 + (kf4 ^ ((row >> 3) & 7))];
                acc[r].x += xv.x * w0.x + xv.y * w1.x + xv.z * w2.x + xv.w * w3.x;
                acc[r].y += xv.x * w0.y + xv.y * w1.y + xv.z * w2.y + xv.w * w3.y;
                acc[r].z += xv.x * w0.z + xv.y * w1.z + xv.z * w2.z + xv.w * w3.z;
                acc[r].w += xv.x * w0.w + xv.y * w1.w + xv.z * w2.w + xv.w * w3.w;
            }
        }
    }

    const int sc = sc4 * 4;
    float4 bv = make_float4(bias[sc], bias[sc + 1], bias[sc + 2], bias[sc + 3]);
#pragma unroll
    for (int r = 0; r < 8; ++r) {
        int gr = row0 + r0 + r;
        if (gr < M) {
            float4 a = acc[r];
            a.x += bv.x; a.y += bv.y; a.z += bv.z; a.w += bv.w;
            if (RES) {
                float4 rv = *(const float4*)&RES[(long long)gr * DD + sc];
                a.x += rv.x; a.y += rv.y; a.z += rv.z; a.w += rv.w;
            }
            if (relu) {
                a.x = fmaxf(a.x, 0.f); a.y = fmaxf(a.y, 0.f);
                a.z = fmaxf(a.z, 0.f); a.w = fmaxf(a.w, 0.f);
            }
            *(float4*)&Y[(long long)gr * DD + sc] = a;
        }
    }
}

// ---------------- final projection: out[M,16] = X[M,128] @ Wo[128,16] + bo ----------------
__global__ __launch_bounds__(256) void k_gemm_out(
        const float* __restrict__ X, const float* __restrict__ Wo,
        const float* __restrict__ bo, float* __restrict__ Y, int M) {
    __shared__ float Wl[128 * 16];
    int t = threadIdx.x;
    for (int i = t * 4; i < 128 * 16; i += 256 * 4) {
        *(float4*)&Wl[i] = *(const float4*)&Wo[i];
    }
    __syncthreads();
    int r = blockIdx.x * blockDim.x + t;
    if (r < M) {
        float acc[16];
#pragma unroll
        for (int j = 0; j < 16; ++j) acc[j] = bo[j];
#pragma unroll
        for (int k = 0; k < 128; k += 4) {
            float4 x = *(const float4*)&X[(long long)r * DD + k];
#pragma unroll
            for (int j = 0; j < 16; ++j) {
                acc[j] += x.x * Wl[(k + 0) * 16 + j] + x.y * Wl[(k + 1) * 16 + j]
                        + x.z * Wl[(k + 2) * 16 + j] + x.w * Wl[(k + 3) * 16 + j];
            }
        }
#pragma unroll
        for (int j = 0; j < 16; j += 4) {
            float4 o = make_float4(acc[j], acc[j + 1], acc[j + 2], acc[j + 3]);
            *(float4*)&Y[(long long)r * CC + j] = o;
        }
    }
}

extern "C" void kernel_launch(void* const* d_in, const int* in_sizes, int n_in,
                              void* d_out, int out_size, void* d_ws, size_t ws_size,
                              hipStream_t stream) {
    const int*   src = (const int*)d_in[0];
    const int*   dst = (const int*)d_in[1];
    const float* inputs = (const float*)d_in[2];
    const float* ew  = (const float*)d_in[3];
    const float* W1  = (const float*)d_in[4];
    const float* b1  = (const float*)d_in[5];
    const float* W2  = (const float*)d_in[6];
    const float* b2  = (const float*)d_in[7];
    const float* W3  = (const float*)d_in[8];
    const float* b3  = (const float*)d_in[9];
    const float* W4  = (const float*)d_in[10];
    const float* b4  = (const float*)d_in[11];
    const float* Wr  = (const float*)d_in[12];
    const float* br  = (const float*)d_in[13];
    const float* Wo  = (const float*)d_in[14];
    const float* bo  = (const float*)d_in[15];
    float* out = (float*)d_out;

    // workspace layout
    char* p = (char*)d_ws;
    float* iso    = (float*)p; p += sizeof(float) * NN;
    float* isi    = (float*)p; p += sizeof(float) * NN;
    int*   cs     = (int*)p;   p += sizeof(int) * NN;
    int*   cd     = (int*)p;   p += sizeof(int) * NN;
    int*   cursor = (int*)p;   p += sizeof(int) * NN;
    int*   rowptr = (int*)p;   p += sizeof(int) * (NN + 1);
    int*   partial= (int*)p;   p += sizeof(int) * NBLK_SCAN;
    int*   pp     = (int*)p;   p += sizeof(int) * NBLK_SCAN;
    p = (char*)(((uintptr_t)p + 255) & ~(uintptr_t)255);
    int2*  pairs  = (int2*)p;  p += sizeof(int2) * EE;
    float* RES    = (float*)p; p += sizeof(float) * (size_t)NN * DD;
    float* G      = (float*)p; p += sizeof(float) * (size_t)NN * DD;
    float* X0     = (float*)p; p += sizeof(float) * (size_t)NN * DD;

    const int GEMM_GRID = (NN + GTILE - 1) / GTILE;   // 782

    // ---- CSR build with folded weights ----
    hipMemsetAsync(cs, 0, sizeof(int) * NN * 3, stream);  // cs, cd, cursor contiguous
    k_degcount<<<(EE + 255) / 256, 256, 0, stream>>>(src, dst, cs, cd);
    k_degfinalize<<<(NN + 255) / 256, 256, 0, stream>>>(cs, cd, iso, isi);
    k_blocksum<<<NBLK_SCAN, SBLK, 0, stream>>>(cd, partial);
    k_scanpartial<<<1, SBLK, 0, stream>>>(partial, pp, rowptr);
    k_writerowptr<<<NBLK_SCAN, SBLK, 0, stream>>>(cd, pp, rowptr);
    k_fill<<<(EE + 255) / 256, 256, 0, stream>>>(src, dst, ew, iso, isi, rowptr, cursor, pairs);

    // ---- res = inputs @ Wr + br ----
    k_gemm128<<<GEMM_GRID, 256, 0, stream>>>(inputs, Wr, br, nullptr, RES, NN, 0);

    const float* Ws[4] = {W1, W2, W3, W4};
    const float* bs[4] = {b1, b2, b3, b4};
    const float* xin = inputs;
    for (int l = 0; l < 4; ++l) {
        k_gather<<<(NN + 3) / 4, 256, 0, stream>>>(xin, rowptr, pairs, G);
        const float* res_p = (l == 3) ? RES : nullptr;
        k_gemm128<<<GEMM_GRID, 256, 0, stream>>>(G, Ws[l], bs[l], res_p, X0, NN, 1);
        xin = X0;
    }

    k_gemm_out<<<(NN + 255) / 256, 256, 0, stream>>>(X0, Wo, bo, out, NN);
}

// Round 8
// 601.342 us; speedup vs baseline: 1.2701x; 1.2701x over previous
//
#include <hip/hip_runtime.h>

#define NN 50000
#define EE 800000
#define DD 128
#define CC 16

typedef __attribute__((ext_vector_type(8))) short bf16x8;
typedef __attribute__((ext_vector_type(4))) float f32x4;

__device__ inline unsigned short f2bf(float x) {
    unsigned int u = __float_as_uint(x);
    unsigned int r = (u + 0x7FFFu + ((u >> 16) & 1u)) >> 16;
    return (unsigned short)r;
}
__device__ inline float bf2f(unsigned short h) {
    return __uint_as_float(((unsigned int)h) << 16);
}

// ---------------- degree counting (int) ----------------
__global__ void k_degcount(const int* __restrict__ src, const int* __restrict__ dst,
                           int* __restrict__ cs, int* __restrict__ cd) {
    int e = blockIdx.x * blockDim.x + threadIdx.x;
    if (e < EE) {
        atomicAdd(&cs[src[e]], 1);
        atomicAdd(&cd[dst[e]], 1);
    }
}

__global__ void k_degfinalize(const int* __restrict__ cs, const int* __restrict__ cd,
                              float* __restrict__ iso, float* __restrict__ isi) {
    int i = blockIdx.x * blockDim.x + threadIdx.x;
    if (i < NN) {
        iso[i] = rsqrtf(fmaxf((float)cs[i], 1.0f));
        isi[i] = rsqrtf(fmaxf((float)cd[i], 1.0f));
    }
}

// ---------------- hierarchical exclusive scan: cd -> rowptr ----------------
#define SBLK 256
#define NBLK_SCAN ((NN + SBLK - 1) / SBLK)   // 196

__global__ __launch_bounds__(SBLK) void k_blocksum(const int* __restrict__ cnt,
                                                   int* __restrict__ partial) {
    __shared__ int s[SBLK];
    int t = threadIdx.x;
    int i = blockIdx.x * SBLK + t;
    int v = (i < NN) ? cnt[i] : 0;
    s[t] = v;
    __syncthreads();
    for (int off = SBLK / 2; off > 0; off >>= 1) {
        if (t < off) s[t] += s[t + off];
        __syncthreads();
    }
    if (t == 0) partial[blockIdx.x] = s[0];
}

__global__ __launch_bounds__(SBLK) void k_scanpartial(const int* __restrict__ partial,
                                                      int* __restrict__ pp,
                                                      int* __restrict__ rowptr) {
    __shared__ int s[SBLK];
    int t = threadIdx.x;
    int v = (t < NBLK_SCAN) ? partial[t] : 0;
    s[t] = v;
    __syncthreads();
    for (int off = 1; off < SBLK; off <<= 1) {
        int x = (t >= off) ? s[t - off] : 0;
        __syncthreads();
        s[t] += x;
        __syncthreads();
    }
    if (t < NBLK_SCAN) pp[t] = s[t] - v;   // exclusive prefix of block partials
    if (t == SBLK - 1) rowptr[NN] = s[t];  // grand total (== EE)
}

__global__ __launch_bounds__(SBLK) void k_writerowptr(const int* __restrict__ cnt,
                                                      const int* __restrict__ pp,
                                                      int* __restrict__ rowptr) {
    __shared__ int s[SBLK];
    int t = threadIdx.x;
    int i = blockIdx.x * SBLK + t;
    int v = (i < NN) ? cnt[i] : 0;
    s[t] = v;
    __syncthreads();
    for (int off = 1; off < SBLK; off <<= 1) {
        int x = (t >= off) ? s[t - off] : 0;
        __syncthreads();
        s[t] += x;
        __syncthreads();
    }
    if (i < NN) rowptr[i] = pp[blockIdx.x] + s[t] - v;
}

// ---------------- CSR fill with folded edge weight (guarded store) ----------------
__global__ void k_fill(const int* __restrict__ src, const int* __restrict__ dst,
                       const float* __restrict__ ew, const float* __restrict__ iso,
                       const float* __restrict__ isi, const int* __restrict__ rowptr,
                       int* __restrict__ cursor, int2* __restrict__ pairs) {
    int e = blockIdx.x * blockDim.x + threadIdx.x;
    if (e < EE) {
        int d = dst[e];
        int s = src[e];
        int pos = atomicAdd(&cursor[d], 1);
        float w = ew[e] * iso[s] * isi[d];
        int2 p;
        p.x = s;
        p.y = __float_as_int(w);
        int idx = rowptr[d] + pos;
        if ((unsigned)idx < EE) pairs[idx] = p;   // defensive: never store wild
    }
}

// ---------------- CSR gather (proven round-6 version, clamped) ----------------
__global__ __launch_bounds__(256) void k_gather(
        const float* __restrict__ X, const int* __restrict__ rowptr,
        const int2* __restrict__ pairs, float* __restrict__ G) {
    int node = blockIdx.x * 4 + (threadIdx.x >> 6);
    if (node >= NN) return;
    int lane = threadIdx.x & 63;
    int c = lane * 2;
    int j = rowptr[node];
    int end = rowptr[node + 1];
    j = max(0, min(j, EE));
    end = max(j, min(end, EE));
    float2 acc = make_float2(0.f, 0.f);
    for (; j + 1 < end; j += 2) {
        int2 p0 = pairs[j];
        int2 p1 = pairs[j + 1];
        int c0 = ((unsigned)p0.x < NN) ? p0.x : 0;
        int c1 = ((unsigned)p1.x < NN) ? p1.x : 0;
        float w0 = __int_as_float(p0.y);
        float w1 = __int_as_float(p1.y);
        float2 h0 = *(const float2*)&X[c0 * DD + c];
        float2 h1 = *(const float2*)&X[c1 * DD + c];
        acc.x = fmaf(h0.x, w0, acc.x);
        acc.y = fmaf(h0.y, w0, acc.y);
        acc.x = fmaf(h1.x, w1, acc.x);
        acc.y = fmaf(h1.y, w1, acc.y);
    }
    if (j < end) {
        int2 p0 = pairs[j];
        int c0 = ((unsigned)p0.x < NN) ? p0.x : 0;
        float w0 = __int_as_float(p0.y);
        float2 h0 = *(const float2*)&X[c0 * DD + c];
        acc.x = fmaf(h0.x, w0, acc.x);
        acc.y = fmaf(h0.y, w0, acc.y);
    }
    *(float2*)&G[node * DD + c] = acc;
}

// ---------------- W prep: fp32 [k][c] -> bf16 hi/lo, layout [c][k ^ ((c&7)<<3)] ----------------
// grid: 5*128 blocks, 128 threads. block b: matrix b>>7, col c = b&127; thread = k.
__global__ __launch_bounds__(128) void k_prepw(
        const float* __restrict__ W1, const float* __restrict__ W2,
        const float* __restrict__ W3, const float* __restrict__ W4,
        const float* __restrict__ Wr,
        unsigned short* __restrict__ WH, unsigned short* __restrict__ WL) {
    int m = blockIdx.x >> 7;
    int c = blockIdx.x & 127;
    int k = threadIdx.x;
    const float* Wm = (m == 0) ? W1 : (m == 1) ? W2 : (m == 2) ? W3 : (m == 3) ? W4 : Wr;
    float x = Wm[k * 128 + c];
    unsigned short hi = f2bf(x);
    unsigned short lo = f2bf(x - bf2f(hi));
    int off = m * 16384 + c * 128 + (k ^ ((c & 7) << 3));
    WH[off] = hi;
    WL[off] = lo;
}

// ---------------- MFMA split-precision GEMM ----------------
// Y[64,128] per block = X[64,128] @ W[128,128] + bias (+RES) (relu?)
// X fp32 -> hi/lo bf16 in LDS (swizzled); W pre-split/pre-swizzled, linear LDS copy.
// 4 waves; wave w: cols [32w,32w+32) = 4 m-frags x 2 n-frags, K=128 in 4 steps.
// acc += Ah*Bh + Ah*Bl + Al*Bh   (residual ~2^-17)
#define GTILE 64
__global__ __launch_bounds__(256) void k_gemm_mfma(
        const float* __restrict__ X,
        const unsigned short* __restrict__ Wh, const unsigned short* __restrict__ Wl,
        const float* __restrict__ bias, const float* __restrict__ RES,
        float* __restrict__ Y, int M, int relu) {
    __shared__ unsigned short Xh[GTILE * 128];
    __shared__ unsigned short Xlo[GTILE * 128];
    __shared__ unsigned short Bh[128 * 128];
    __shared__ unsigned short Bl[128 * 128];

    const int t = threadIdx.x;
    const int row0 = blockIdx.x * GTILE;
    const float4* X4 = (const float4*)X;

    // stage X: 2048 float4 groups -> hi/lo bf16, swizzled
    for (int i = t; i < GTILE * 32; i += 256) {
        int r = i >> 5;
        int c4 = i & 31;
        int gr = row0 + r;
        float4 v = make_float4(0.f, 0.f, 0.f, 0.f);
        if (gr < M) v = X4[(long long)gr * 32 + c4];
        ushort4 h, lo;
        h.x = f2bf(v.x); lo.x = f2bf(v.x - bf2f(h.x));
        h.y = f2bf(v.y); lo.y = f2bf(v.y - bf2f(h.y));
        h.z = f2bf(v.z); lo.z = f2bf(v.z - bf2f(h.z));
        h.w = f2bf(v.w); lo.w = f2bf(v.w - bf2f(h.w));
        int base = r * 128 + ((c4 * 4) ^ ((r & 7) << 3));
        *(ushort4*)&Xh[base] = h;
        *(ushort4*)&Xlo[base] = lo;
    }
    // stage W: linear copy (pre-swizzled in global)
    {
        const uint4* src_h = (const uint4*)Wh;
        const uint4* src_l = (const uint4*)Wl;
        uint4* dst_h = (uint4*)Bh;
        uint4* dst_l = (uint4*)Bl;
        for (int i = t; i < 2048; i += 256) {
            dst_h[i] = src_h[i];
            dst_l[i] = src_l[i];
        }
    }
    __syncthreads();

    const int lane = t & 63;
    const int wav = t >> 6;
    const int colb = wav * 32;
    const int lr = lane & 15;
    const int lk = lane >> 4;

    f32x4 acc[4][2];
#pragma unroll
    for (int m = 0; m < 4; ++m)
#pragma unroll
        for (int n = 0; n < 2; ++n) acc[m][n] = (f32x4){0.f, 0.f, 0.f, 0.f};

#pragma unroll
    for (int k0 = 0; k0 < 4; ++k0) {
        const int kbase = k0 * 32 + lk * 8;
        bf16x8 ah[4], al[4], bh[2], bl[2];
#pragma unroll
        for (int m = 0; m < 4; ++m) {
            int row = 16 * m + lr;
            int off = row * 128 + (kbase ^ ((row & 7) << 3));
            ah[m] = *(const bf16x8*)&Xh[off];
            al[m] = *(const bf16x8*)&Xlo[off];
        }
#pragma unroll
        for (int n = 0; n < 2; ++n) {
            int c = colb + 16 * n + lr;
            int off = c * 128 + (kbase ^ ((c & 7) << 3));
            bh[n] = *(const bf16x8*)&Bh[off];
            bl[n] = *(const bf16x8*)&Bl[off];
        }
#pragma unroll
        for (int m = 0; m < 4; ++m)
#pragma unroll
            for (int n = 0; n < 2; ++n) {
                acc[m][n] = __builtin_amdgcn_mfma_f32_16x16x32_bf16(ah[m], bh[n], acc[m][n], 0, 0, 0);
                acc[m][n] = __builtin_amdgcn_mfma_f32_16x16x32_bf16(ah[m], bl[n], acc[m][n], 0, 0, 0);
                acc[m][n] = __builtin_amdgcn_mfma_f32_16x16x32_bf16(al[m], bh[n], acc[m][n], 0, 0, 0);
            }
    }

    // epilogue: C/D layout col = lane&15, row = (lane>>4)*4 + j  (m89-verified)
#pragma unroll
    for (int n = 0; n < 2; ++n) {
        int gc = colb + 16 * n + lr;
        float bv = bias[gc];
#pragma unroll
        for (int m = 0; m < 4; ++m) {
#pragma unroll
            for (int j = 0; j < 4; ++j) {
                int gr = row0 + 16 * m + lk * 4 + j;
                if (gr < M) {
                    float a = acc[m][n][j] + bv;
                    if (RES) a += RES[(long long)gr * DD + gc];
                    if (relu) a = fmaxf(a, 0.f);
                    Y[(long long)gr * DD + gc] = a;
                }
            }
        }
    }
}

// ---------------- final projection: out[M,16] = X[M,128] @ Wo[128,16] + bo ----------------
__global__ __launch_bounds__(256) void k_gemm_out(
        const float* __restrict__ X, const float* __restrict__ Wo,
        const float* __restrict__ bo, float* __restrict__ Y, int M) {
    __shared__ float Wlds[128 * 16];
    int t = threadIdx.x;
    for (int i = t * 4; i < 128 * 16; i += 256 * 4) {
        *(float4*)&Wlds[i] = *(const float4*)&Wo[i];
    }
    __syncthreads();
    int r = blockIdx.x * blockDim.x + t;
    if (r < M) {
        float acc[16];
#pragma unroll
        for (int j = 0; j < 16; ++j) acc[j] = bo[j];
#pragma unroll
        for (int k = 0; k < 128; k += 4) {
            float4 x = *(const float4*)&X[(long long)r * DD + k];
#pragma unroll
            for (int j = 0; j < 16; ++j) {
                acc[j] += x.x * Wlds[(k + 0) * 16 + j] + x.y * Wlds[(k + 1) * 16 + j]
                        + x.z * Wlds[(k + 2) * 16 + j] + x.w * Wlds[(k + 3) * 16 + j];
            }
        }
#pragma unroll
        for (int j = 0; j < 16; j += 4) {
            float4 o = make_float4(acc[j], acc[j + 1], acc[j + 2], acc[j + 3]);
            *(float4*)&Y[(long long)r * CC + j] = o;
        }
    }
}

extern "C" void kernel_launch(void* const* d_in, const int* in_sizes, int n_in,
                              void* d_out, int out_size, void* d_ws, size_t ws_size,
                              hipStream_t stream) {
    const int*   src = (const int*)d_in[0];
    const int*   dst = (const int*)d_in[1];
    const float* inputs = (const float*)d_in[2];
    const float* ew  = (const float*)d_in[3];
    const float* W1  = (const float*)d_in[4];
    const float* b1  = (const float*)d_in[5];
    const float* W2  = (const float*)d_in[6];
    const float* b2  = (const float*)d_in[7];
    const float* W3  = (const float*)d_in[8];
    const float* b3  = (const float*)d_in[9];
    const float* W4  = (const float*)d_in[10];
    const float* b4  = (const float*)d_in[11];
    const float* Wr  = (const float*)d_in[12];
    const float* br  = (const float*)d_in[13];
    const float* Wo  = (const float*)d_in[14];
    const float* bo  = (const float*)d_in[15];
    float* out = (float*)d_out;

    // workspace layout
    char* p = (char*)d_ws;
    float* iso    = (float*)p; p += sizeof(float) * NN;
    float* isi    = (float*)p; p += sizeof(float) * NN;
    int*   cs     = (int*)p;   p += sizeof(int) * NN;      // reused as WHg after fill
    int*   cd     = (int*)p;   p += sizeof(int) * NN;
    int*   cursor = (int*)p;   p += sizeof(int) * NN;
    int*   rowptr = (int*)p;   p += sizeof(int) * (NN + 1);
    int*   partial= (int*)p;   p += sizeof(int) * NBLK_SCAN;
    int*   pp     = (int*)p;   p += sizeof(int) * NBLK_SCAN;
    p = (char*)(((uintptr_t)p + 255) & ~(uintptr_t)255);
    int2*  pairs  = (int2*)p;  p += sizeof(int2) * EE;
    float* RES    = (float*)p; p += sizeof(float) * (size_t)NN * DD;
    float* G      = (float*)p; p += sizeof(float) * (size_t)NN * DD;
    float* X0     = (float*)p; p += sizeof(float) * (size_t)NN * DD;

    // bf16 weight buffers alias the (dead-after-fill) cs/cd/cursor region:
    // need 2 * 5*16384*2B = 320KB; cs..cursor = 600KB. 16B-aligned (offset 400000).
    unsigned short* WHg = (unsigned short*)cs;           // 5*16384 ushorts = 160KB
    unsigned short* WLg = WHg + 5 * 16384;               // 160KB

    const int GEMM_GRID = (NN + GTILE - 1) / GTILE;      // 782

    // ---- CSR build with folded weights ----
    hipMemsetAsync(cs, 0, sizeof(int) * NN * 3, stream);  // cs, cd, cursor contiguous
    k_degcount<<<(EE + 255) / 256, 256, 0, stream>>>(src, dst, cs, cd);
    k_degfinalize<<<(NN + 255) / 256, 256, 0, stream>>>(cs, cd, iso, isi);
    k_blocksum<<<NBLK_SCAN, SBLK, 0, stream>>>(cd, partial);
    k_scanpartial<<<1, SBLK, 0, stream>>>(partial, pp, rowptr);
    k_writerowptr<<<NBLK_SCAN, SBLK, 0, stream>>>(cd, pp, rowptr);
    k_fill<<<(EE + 255) / 256, 256, 0, stream>>>(src, dst, ew, iso, isi, rowptr, cursor, pairs);

    // ---- prep bf16 hi/lo weights (after fill: cs/cd/cursor are dead) ----
    k_prepw<<<5 * 128, 128, 0, stream>>>(W1, W2, W3, W4, Wr, WHg, WLg);

    // ---- res = inputs @ Wr + br ----
    k_gemm_mfma<<<GEMM_GRID, 256, 0, stream>>>(inputs, WHg + 4 * 16384, WLg + 4 * 16384,
                                               br, nullptr, RES, NN, 0);

    const float* bs[4] = {b1, b2, b3, b4};
    const float* xin = inputs;
    for (int l = 0; l < 4; ++l) {
        k_gather<<<(NN + 3) / 4, 256, 0, stream>>>(xin, rowptr, pairs, G);
        const float* res_p = (l == 3) ? RES : nullptr;
        k_gemm_mfma<<<GEMM_GRID, 256, 0, stream>>>(G, WHg + l * 16384, WLg + l * 16384,
                                                   bs[l], res_p, X0, NN, 1);
        xin = X0;
    }

    k_gemm_out<<<(NN + 255) / 256, 256, 0, stream>>>(X0, Wo, bo, out, NN);
}

// Round 9
// 581.175 us; speedup vs baseline: 1.3142x; 1.0347x over previous
//
#include <hip/hip_runtime.h>

#define NN 50000
#define EE 800000
#define DD 128
#define CC 16
#define HCOPIES 64

typedef __attribute__((ext_vector_type(8))) short bf16x8;
typedef __attribute__((ext_vector_type(4))) float f32x4;

__device__ inline unsigned short f2bf(float x) {
    unsigned int u = __float_as_uint(x);
    unsigned int r = (u + 0x7FFFu + ((u >> 16) & 1u)) >> 16;
    return (unsigned short)r;
}
__device__ inline float bf2f(unsigned short h) {
    return __uint_as_float(((unsigned int)h) << 16);
}

// ---------------- privatized degree histogram (packed: src lo16, dst hi16) ----------------
__global__ void k_hist(const int* __restrict__ src, const int* __restrict__ dst,
                       unsigned int* __restrict__ hist) {
    int e = blockIdx.x * blockDim.x + threadIdx.x;
    unsigned int cpy = blockIdx.x & (HCOPIES - 1);
    if (e < EE) {
        int s = src[e];
        int d = dst[e];
        if ((unsigned)s < NN) atomicAdd(&hist[cpy * NN + s], 1u);
        if ((unsigned)d < NN) atomicAdd(&hist[cpy * NN + d], 0x10000u);
    }
}

__global__ void k_reduce_deg(const unsigned int* __restrict__ hist,
                             int* __restrict__ cd,
                             float* __restrict__ iso, float* __restrict__ isi) {
    int i = blockIdx.x * blockDim.x + threadIdx.x;
    if (i < NN) {
        unsigned int sum = 0;
#pragma unroll
        for (int c = 0; c < HCOPIES; ++c) sum += hist[c * NN + i];
        unsigned int csv = sum & 0xFFFFu;
        unsigned int cdv = sum >> 16;
        cd[i] = (int)cdv;
        iso[i] = rsqrtf(fmaxf((float)csv, 1.0f));
        isi[i] = rsqrtf(fmaxf((float)cdv, 1.0f));
    }
}

// ---------------- hierarchical exclusive scan: cd -> rowptr ----------------
#define SBLK 256
#define NBLK_SCAN ((NN + SBLK - 1) / SBLK)   // 196

__global__ __launch_bounds__(SBLK) void k_blocksum(const int* __restrict__ cnt,
                                                   int* __restrict__ partial) {
    __shared__ int s[SBLK];
    int t = threadIdx.x;
    int i = blockIdx.x * SBLK + t;
    int v = (i < NN) ? cnt[i] : 0;
    s[t] = v;
    __syncthreads();
    for (int off = SBLK / 2; off > 0; off >>= 1) {
        if (t < off) s[t] += s[t + off];
        __syncthreads();
    }
    if (t == 0) partial[blockIdx.x] = s[0];
}

__global__ __launch_bounds__(SBLK) void k_scanpartial(const int* __restrict__ partial,
                                                      int* __restrict__ pp,
                                                      int* __restrict__ rowptr) {
    __shared__ int s[SBLK];
    int t = threadIdx.x;
    int v = (t < NBLK_SCAN) ? partial[t] : 0;
    s[t] = v;
    __syncthreads();
    for (int off = 1; off < SBLK; off <<= 1) {
        int x = (t >= off) ? s[t - off] : 0;
        __syncthreads();
        s[t] += x;
        __syncthreads();
    }
    if (t < NBLK_SCAN) pp[t] = s[t] - v;   // exclusive prefix of block partials
    if (t == SBLK - 1) rowptr[NN] = s[t];  // grand total (== EE)
}

__global__ __launch_bounds__(SBLK) void k_writerowptr(const int* __restrict__ cnt,
                                                      const int* __restrict__ pp,
                                                      int* __restrict__ rowptr) {
    __shared__ int s[SBLK];
    int t = threadIdx.x;
    int i = blockIdx.x * SBLK + t;
    int v = (i < NN) ? cnt[i] : 0;
    s[t] = v;
    __syncthreads();
    for (int off = 1; off < SBLK; off <<= 1) {
        int x = (t >= off) ? s[t - off] : 0;
        __syncthreads();
        s[t] += x;
        __syncthreads();
    }
    if (i < NN) rowptr[i] = pp[blockIdx.x] + s[t] - v;
}

// ---------------- CSR fill with folded edge weight (guarded store) ----------------
__global__ void k_fill(const int* __restrict__ src, const int* __restrict__ dst,
                       const float* __restrict__ ew, const float* __restrict__ iso,
                       const float* __restrict__ isi, const int* __restrict__ rowptr,
                       int* __restrict__ cursor, int2* __restrict__ pairs) {
    int e = blockIdx.x * blockDim.x + threadIdx.x;
    if (e < EE) {
        int d = dst[e];
        int s = src[e];
        int pos = atomicAdd(&cursor[d], 1);
        float w = ew[e] * iso[s] * isi[d];
        int2 p;
        p.x = s;
        p.y = __float_as_int(w);
        int idx = rowptr[d] + pos;
        if ((unsigned)idx < EE) pairs[idx] = p;   // defensive: never store wild
    }
}

// ---------------- CSR gather, fp32 source (layer 0 / inputs) ----------------
__global__ __launch_bounds__(256) void k_gather(
        const float* __restrict__ X, const int* __restrict__ rowptr,
        const int2* __restrict__ pairs, float* __restrict__ G) {
    int node = blockIdx.x * 4 + (threadIdx.x >> 6);
    if (node >= NN) return;
    int lane = threadIdx.x & 63;
    int c = lane * 2;
    int j = rowptr[node];
    int end = rowptr[node + 1];
    j = max(0, min(j, EE));
    end = max(j, min(end, EE));
    float2 acc = make_float2(0.f, 0.f);
    for (; j + 1 < end; j += 2) {
        int2 p0 = pairs[j];
        int2 p1 = pairs[j + 1];
        int c0 = ((unsigned)p0.x < NN) ? p0.x : 0;
        int c1 = ((unsigned)p1.x < NN) ? p1.x : 0;
        float w0 = __int_as_float(p0.y);
        float w1 = __int_as_float(p1.y);
        float2 h0 = *(const float2*)&X[c0 * DD + c];
        float2 h1 = *(const float2*)&X[c1 * DD + c];
        acc.x = fmaf(h0.x, w0, acc.x);
        acc.y = fmaf(h0.y, w0, acc.y);
        acc.x = fmaf(h1.x, w1, acc.x);
        acc.y = fmaf(h1.y, w1, acc.y);
    }
    if (j < end) {
        int2 p0 = pairs[j];
        int c0 = ((unsigned)p0.x < NN) ? p0.x : 0;
        float w0 = __int_as_float(p0.y);
        float2 h0 = *(const float2*)&X[c0 * DD + c];
        acc.x = fmaf(h0.x, w0, acc.x);
        acc.y = fmaf(h0.y, w0, acc.y);
    }
    *(float2*)&G[node * DD + c] = acc;
}

// ---------------- CSR gather, bf16 source (layers 1-3; halves read traffic) ----------------
__global__ __launch_bounds__(256) void k_gather_bf(
        const unsigned short* __restrict__ H, const int* __restrict__ rowptr,
        const int2* __restrict__ pairs, float* __restrict__ G) {
    int node = blockIdx.x * 4 + (threadIdx.x >> 6);
    if (node >= NN) return;
    int lane = threadIdx.x & 63;
    int c = lane * 2;
    int j = rowptr[node];
    int end = rowptr[node + 1];
    j = max(0, min(j, EE));
    end = max(j, min(end, EE));
    float2 acc = make_float2(0.f, 0.f);
    for (; j + 1 < end; j += 2) {
        int2 p0 = pairs[j];
        int2 p1 = pairs[j + 1];
        int c0 = ((unsigned)p0.x < NN) ? p0.x : 0;
        int c1 = ((unsigned)p1.x < NN) ? p1.x : 0;
        float w0 = __int_as_float(p0.y);
        float w1 = __int_as_float(p1.y);
        ushort2 h0 = *(const ushort2*)&H[c0 * DD + c];
        ushort2 h1 = *(const ushort2*)&H[c1 * DD + c];
        acc.x = fmaf(bf2f(h0.x), w0, acc.x);
        acc.y = fmaf(bf2f(h0.y), w0, acc.y);
        acc.x = fmaf(bf2f(h1.x), w1, acc.x);
        acc.y = fmaf(bf2f(h1.y), w1, acc.y);
    }
    if (j < end) {
        int2 p0 = pairs[j];
        int c0 = ((unsigned)p0.x < NN) ? p0.x : 0;
        float w0 = __int_as_float(p0.y);
        ushort2 h0 = *(const ushort2*)&H[c0 * DD + c];
        acc.x = fmaf(bf2f(h0.x), w0, acc.x);
        acc.y = fmaf(bf2f(h0.y), w0, acc.y);
    }
    *(float2*)&G[node * DD + c] = acc;
}

// ---------------- W prep: fp32 [k][c] -> bf16 hi/lo, layout [c][k ^ ((c&7)<<3)] ----------------
__global__ __launch_bounds__(128) void k_prepw(
        const float* __restrict__ W1, const float* __restrict__ W2,
        const float* __restrict__ W3, const float* __restrict__ W4,
        const float* __restrict__ Wr,
        unsigned short* __restrict__ WH, unsigned short* __restrict__ WL) {
    int m = blockIdx.x >> 7;
    int c = blockIdx.x & 127;
    int k = threadIdx.x;
    const float* Wm = (m == 0) ? W1 : (m == 1) ? W2 : (m == 2) ? W3 : (m == 3) ? W4 : Wr;
    float x = Wm[k * 128 + c];
    unsigned short hi = f2bf(x);
    unsigned short lo = f2bf(x - bf2f(hi));
    int off = m * 16384 + c * 128 + (k ^ ((c & 7) << 3));
    WH[off] = hi;
    WL[off] = lo;
}

// ---------------- MFMA split-precision GEMM ----------------
// Y[64,128] per block = X[64,128] @ W[128,128] + bias (+RES) (relu?)
// acc += Ah*Bh + Ah*Bl + Al*Bh   (residual ~2^-17)
// Output: Yb non-null -> bf16 store; else fp32 to Yf.
#define GTILE 64
__global__ __launch_bounds__(256) void k_gemm_mfma(
        const float* __restrict__ X,
        const unsigned short* __restrict__ Wh, const unsigned short* __restrict__ Wl,
        const float* __restrict__ bias, const float* __restrict__ RES,
        float* __restrict__ Yf, unsigned short* __restrict__ Yb, int M, int relu) {
    __shared__ unsigned short Xh[GTILE * 128];
    __shared__ unsigned short Xlo[GTILE * 128];
    __shared__ unsigned short Bh[128 * 128];
    __shared__ unsigned short Bl[128 * 128];

    const int t = threadIdx.x;
    const int row0 = blockIdx.x * GTILE;
    const float4* X4 = (const float4*)X;

    // stage X: fp32 -> hi/lo bf16, swizzled
    for (int i = t; i < GTILE * 32; i += 256) {
        int r = i >> 5;
        int c4 = i & 31;
        int gr = row0 + r;
        float4 v = make_float4(0.f, 0.f, 0.f, 0.f);
        if (gr < M) v = X4[(long long)gr * 32 + c4];
        ushort4 h, lo;
        h.x = f2bf(v.x); lo.x = f2bf(v.x - bf2f(h.x));
        h.y = f2bf(v.y); lo.y = f2bf(v.y - bf2f(h.y));
        h.z = f2bf(v.z); lo.z = f2bf(v.z - bf2f(h.z));
        h.w = f2bf(v.w); lo.w = f2bf(v.w - bf2f(h.w));
        int base = r * 128 + ((c4 * 4) ^ ((r & 7) << 3));
        *(ushort4*)&Xh[base] = h;
        *(ushort4*)&Xlo[base] = lo;
    }
    // stage W: linear copy (pre-swizzled in global)
    {
        const uint4* src_h = (const uint4*)Wh;
        const uint4* src_l = (const uint4*)Wl;
        uint4* dst_h = (uint4*)Bh;
        uint4* dst_l = (uint4*)Bl;
        for (int i = t; i < 2048; i += 256) {
            dst_h[i] = src_h[i];
            dst_l[i] = src_l[i];
        }
    }
    __syncthreads();

    const int lane = t & 63;
    const int wav = t >> 6;
    const int colb = wav * 32;
    const int lr = lane & 15;
    const int lk = lane >> 4;

    f32x4 acc[4][2];
#pragma unroll
    for (int m = 0; m < 4; ++m)
#pragma unroll
        for (int n = 0; n < 2; ++n) acc[m][n] = (f32x4){0.f, 0.f, 0.f, 0.f};

#pragma unroll
    for (int k0 = 0; k0 < 4; ++k0) {
        const int kbase = k0 * 32 + lk * 8;
        bf16x8 ah[4], al[4], bh[2], bl[2];
#pragma unroll
        for (int m = 0; m < 4; ++m) {
            int row = 16 * m + lr;
            int off = row * 128 + (kbase ^ ((row & 7) << 3));
            ah[m] = *(const bf16x8*)&Xh[off];
            al[m] = *(const bf16x8*)&Xlo[off];
        }
#pragma unroll
        for (int n = 0; n < 2; ++n) {
            int c = colb + 16 * n + lr;
            int off = c * 128 + (kbase ^ ((c & 7) << 3));
            bh[n] = *(const bf16x8*)&Bh[off];
            bl[n] = *(const bf16x8*)&Bl[off];
        }
#pragma unroll
        for (int m = 0; m < 4; ++m)
#pragma unroll
            for (int n = 0; n < 2; ++n) {
                acc[m][n] = __builtin_amdgcn_mfma_f32_16x16x32_bf16(ah[m], bh[n], acc[m][n], 0, 0, 0);
                acc[m][n] = __builtin_amdgcn_mfma_f32_16x16x32_bf16(ah[m], bl[n], acc[m][n], 0, 0, 0);
                acc[m][n] = __builtin_amdgcn_mfma_f32_16x16x32_bf16(al[m], bh[n], acc[m][n], 0, 0, 0);
            }
    }

    // epilogue: C/D layout col = lane&15, row = (lane>>4)*4 + j
#pragma unroll
    for (int n = 0; n < 2; ++n) {
        int gc = colb + 16 * n + lr;
        float bv = bias[gc];
#pragma unroll
        for (int m = 0; m < 4; ++m) {
#pragma unroll
            for (int j = 0; j < 4; ++j) {
                int gr = row0 + 16 * m + lk * 4 + j;
                if (gr < M) {
                    float a = acc[m][n][j] + bv;
                    if (RES) a += RES[(long long)gr * DD + gc];
                    if (relu) a = fmaxf(a, 0.f);
                    if (Yb) Yb[(long long)gr * DD + gc] = f2bf(a);
                    else    Yf[(long long)gr * DD + gc] = a;
                }
            }
        }
    }
}

// ---------------- final projection: out[M,16] = X[M,128] @ Wo[128,16] + bo ----------------
__global__ __launch_bounds__(256) void k_gemm_out(
        const float* __restrict__ X, const float* __restrict__ Wo,
        const float* __restrict__ bo, float* __restrict__ Y, int M) {
    __shared__ float Wlds[128 * 16];
    int t = threadIdx.x;
    for (int i = t * 4; i < 128 * 16; i += 256 * 4) {
        *(float4*)&Wlds[i] = *(const float4*)&Wo[i];
    }
    __syncthreads();
    int r = blockIdx.x * blockDim.x + t;
    if (r < M) {
        float acc[16];
#pragma unroll
        for (int j = 0; j < 16; ++j) acc[j] = bo[j];
#pragma unroll
        for (int k = 0; k < 128; k += 4) {
            float4 x = *(const float4*)&X[(long long)r * DD + k];
#pragma unroll
            for (int j = 0; j < 16; ++j) {
                acc[j] += x.x * Wlds[(k + 0) * 16 + j] + x.y * Wlds[(k + 1) * 16 + j]
                        + x.z * Wlds[(k + 2) * 16 + j] + x.w * Wlds[(k + 3) * 16 + j];
            }
        }
#pragma unroll
        for (int j = 0; j < 16; j += 4) {
            float4 o = make_float4(acc[j], acc[j + 1], acc[j + 2], acc[j + 3]);
            *(float4*)&Y[(long long)r * CC + j] = o;
        }
    }
}

extern "C" void kernel_launch(void* const* d_in, const int* in_sizes, int n_in,
                              void* d_out, int out_size, void* d_ws, size_t ws_size,
                              hipStream_t stream) {
    const int*   src = (const int*)d_in[0];
    const int*   dst = (const int*)d_in[1];
    const float* inputs = (const float*)d_in[2];
    const float* ew  = (const float*)d_in[3];
    const float* W1  = (const float*)d_in[4];
    const float* b1  = (const float*)d_in[5];
    const float* W2  = (const float*)d_in[6];
    const float* b2  = (const float*)d_in[7];
    const float* W3  = (const float*)d_in[8];
    const float* b3  = (const float*)d_in[9];
    const float* W4  = (const float*)d_in[10];
    const float* b4  = (const float*)d_in[11];
    const float* Wr  = (const float*)d_in[12];
    const float* br  = (const float*)d_in[13];
    const float* Wo  = (const float*)d_in[14];
    const float* bo  = (const float*)d_in[15];
    float* out = (float*)d_out;

    // workspace layout
    char* p = (char*)d_ws;
    float* iso    = (float*)p; p += sizeof(float) * NN;
    float* isi    = (float*)p; p += sizeof(float) * NN;
    int*   cs     = (int*)p;   p += sizeof(int) * NN;      // reused as WHg after fill
    int*   cd     = (int*)p;   p += sizeof(int) * NN;
    int*   cursor = (int*)p;   p += sizeof(int) * NN;
    int*   rowptr = (int*)p;   p += sizeof(int) * (NN + 1);
    int*   partial= (int*)p;   p += sizeof(int) * NBLK_SCAN;
    int*   pp     = (int*)p;   p += sizeof(int) * NBLK_SCAN;
    p = (char*)(((uintptr_t)p + 255) & ~(uintptr_t)255);
    int2*  pairs  = (int2*)p;  p += sizeof(int2) * EE;
    float* RES    = (float*)p; p += sizeof(float) * (size_t)NN * DD;
    float* G      = (float*)p; p += sizeof(float) * (size_t)NN * DD;
    float* X0     = (float*)p; p += sizeof(float) * (size_t)NN * DD;

    // aliases:
    unsigned short* WHg = (unsigned short*)cs;            // 160KB over cs + part of cd
    unsigned short* WLg = WHg + 5 * 16384;                // 160KB (ends before cursor)
    unsigned int*   hist = (unsigned int*)G;              // 64 copies x 50K packed = 12.8MB
    unsigned short* H   = (unsigned short*)X0;            // bf16 intermediate (12.8MB)

    const int GEMM_GRID = (NN + GTILE - 1) / GTILE;       // 782

    // ---- degrees via privatized histogram (on G region) ----
    hipMemsetAsync(hist, 0, sizeof(unsigned int) * (size_t)HCOPIES * NN, stream);
    hipMemsetAsync(cursor, 0, sizeof(int) * NN, stream);
    k_hist<<<(EE + 255) / 256, 256, 0, stream>>>(src, dst, hist);
    k_reduce_deg<<<(NN + 255) / 256, 256, 0, stream>>>(hist, cd, iso, isi);
    k_blocksum<<<NBLK_SCAN, SBLK, 0, stream>>>(cd, partial);
    k_scanpartial<<<1, SBLK, 0, stream>>>(partial, pp, rowptr);
    k_writerowptr<<<NBLK_SCAN, SBLK, 0, stream>>>(cd, pp, rowptr);
    k_fill<<<(EE + 255) / 256, 256, 0, stream>>>(src, dst, ew, iso, isi, rowptr, cursor, pairs);

    // ---- prep bf16 hi/lo weights (after fill: cs/cd dead) ----
    k_prepw<<<5 * 128, 128, 0, stream>>>(W1, W2, W3, W4, Wr, WHg, WLg);

    // ---- res = inputs @ Wr + br (fp32 out) ----
    k_gemm_mfma<<<GEMM_GRID, 256, 0, stream>>>(inputs, WHg + 4 * 16384, WLg + 4 * 16384,
                                               br, nullptr, RES, nullptr, NN, 0);

    const float* bs[4] = {b1, b2, b3, b4};
    for (int l = 0; l < 4; ++l) {
        if (l == 0)
            k_gather<<<(NN + 3) / 4, 256, 0, stream>>>(inputs, rowptr, pairs, G);
        else
            k_gather_bf<<<(NN + 3) / 4, 256, 0, stream>>>(H, rowptr, pairs, G);

        if (l < 3) {
            // bf16 output -> feeds next gather only
            k_gemm_mfma<<<GEMM_GRID, 256, 0, stream>>>(G, WHg + l * 16384, WLg + l * 16384,
                                                       bs[l], nullptr, nullptr, H, NN, 1);
        } else {
            // final conv layer: +RES, relu, fp32 out
            k_gemm_mfma<<<GEMM_GRID, 256, 0, stream>>>(G, WHg + l * 16384, WLg + l * 16384,
                                                       bs[l], RES, X0, nullptr, NN, 1);
        }
    }

    k_gemm_out<<<(NN + 255) / 256, 256, 0, stream>>>(X0, Wo, bo, out, NN);
}

// Round 10
// 444.942 us; speedup vs baseline: 1.7165x; 1.3062x over previous
//
#include <hip/hip_runtime.h>

#define NN 50000
#define EE 800000
#define DD 128
#define CC 16
#define HCOPIES 64

typedef __attribute__((ext_vector_type(8))) short bf16x8;
typedef __attribute__((ext_vector_type(4))) float f32x4;

__device__ inline unsigned short f2bf(float x) {
    unsigned int u = __float_as_uint(x);
    unsigned int r = (u + 0x7FFFu + ((u >> 16) & 1u)) >> 16;
    return (unsigned short)r;
}
__device__ inline float bf2f(unsigned short h) {
    return __uint_as_float(((unsigned int)h) << 16);
}

// ---------------- privatized degree histogram (packed: src lo16, dst hi16) ----------------
__global__ void k_hist(const int* __restrict__ src, const int* __restrict__ dst,
                       unsigned int* __restrict__ hist) {
    int e = blockIdx.x * blockDim.x + threadIdx.x;
    unsigned int cpy = blockIdx.x & (HCOPIES - 1);
    if (e < EE) {
        int s = src[e];
        int d = dst[e];
        if ((unsigned)s < NN) atomicAdd(&hist[cpy * NN + s], 1u);
        if ((unsigned)d < NN) atomicAdd(&hist[cpy * NN + d], 0x10000u);
    }
}

__global__ void k_reduce_deg(const unsigned int* __restrict__ hist,
                             int* __restrict__ cd,
                             float* __restrict__ iso, float* __restrict__ isi) {
    int i = blockIdx.x * blockDim.x + threadIdx.x;
    if (i < NN) {
        unsigned int sum = 0;
#pragma unroll
        for (int c = 0; c < HCOPIES; ++c) sum += hist[c * NN + i];
        unsigned int csv = sum & 0xFFFFu;
        unsigned int cdv = sum >> 16;
        cd[i] = (int)cdv;
        iso[i] = rsqrtf(fmaxf((float)csv, 1.0f));
        isi[i] = rsqrtf(fmaxf((float)cdv, 1.0f));
    }
}

// ---------------- hierarchical exclusive scan: cd -> rowptr ----------------
#define SBLK 256
#define NBLK_SCAN ((NN + SBLK - 1) / SBLK)   // 196

__global__ __launch_bounds__(SBLK) void k_blocksum(const int* __restrict__ cnt,
                                                   int* __restrict__ partial) {
    __shared__ int s[SBLK];
    int t = threadIdx.x;
    int i = blockIdx.x * SBLK + t;
    int v = (i < NN) ? cnt[i] : 0;
    s[t] = v;
    __syncthreads();
    for (int off = SBLK / 2; off > 0; off >>= 1) {
        if (t < off) s[t] += s[t + off];
        __syncthreads();
    }
    if (t == 0) partial[blockIdx.x] = s[0];
}

__global__ __launch_bounds__(SBLK) void k_scanpartial(const int* __restrict__ partial,
                                                      int* __restrict__ pp,
                                                      int* __restrict__ rowptr) {
    __shared__ int s[SBLK];
    int t = threadIdx.x;
    int v = (t < NBLK_SCAN) ? partial[t] : 0;
    s[t] = v;
    __syncthreads();
    for (int off = 1; off < SBLK; off <<= 1) {
        int x = (t >= off) ? s[t - off] : 0;
        __syncthreads();
        s[t] += x;
        __syncthreads();
    }
    if (t < NBLK_SCAN) pp[t] = s[t] - v;   // exclusive prefix of block partials
    if (t == SBLK - 1) rowptr[NN] = s[t];  // grand total (== EE)
}

__global__ __launch_bounds__(SBLK) void k_writerowptr(const int* __restrict__ cnt,
                                                      const int* __restrict__ pp,
                                                      int* __restrict__ rowptr) {
    __shared__ int s[SBLK];
    int t = threadIdx.x;
    int i = blockIdx.x * SBLK + t;
    int v = (i < NN) ? cnt[i] : 0;
    s[t] = v;
    __syncthreads();
    for (int off = 1; off < SBLK; off <<= 1) {
        int x = (t >= off) ? s[t - off] : 0;
        __syncthreads();
        s[t] += x;
        __syncthreads();
    }
    if (i < NN) rowptr[i] = pp[blockIdx.x] + s[t] - v;
}

// ---------------- CSR fill with folded edge weight (guarded store) ----------------
__global__ void k_fill(const int* __restrict__ src, const int* __restrict__ dst,
                       const float* __restrict__ ew, const float* __restrict__ iso,
                       const float* __restrict__ isi, const int* __restrict__ rowptr,
                       int* __restrict__ cursor, int2* __restrict__ pairs) {
    int e = blockIdx.x * blockDim.x + threadIdx.x;
    if (e < EE) {
        int d = dst[e];
        int s = src[e];
        int pos = atomicAdd(&cursor[d], 1);
        float w = ew[e] * iso[s] * isi[d];
        int2 p;
        p.x = s;
        p.y = __float_as_int(w);
        int idx = rowptr[d] + pos;
        if ((unsigned)idx < EE) pairs[idx] = p;   // defensive: never store wild
    }
}

// ---------------- CSR gather, fp32 source (layer 0 / inputs) ----------------
__global__ __launch_bounds__(256) void k_gather(
        const float* __restrict__ X, const int* __restrict__ rowptr,
        const int2* __restrict__ pairs, float* __restrict__ G) {
    int node = blockIdx.x * 4 + (threadIdx.x >> 6);
    if (node >= NN) return;
    int lane = threadIdx.x & 63;
    int c = lane * 2;
    int j = rowptr[node];
    int end = rowptr[node + 1];
    j = max(0, min(j, EE));
    end = max(j, min(end, EE));
    float2 acc = make_float2(0.f, 0.f);
    for (; j + 1 < end; j += 2) {
        int2 p0 = pairs[j];
        int2 p1 = pairs[j + 1];
        int c0 = ((unsigned)p0.x < NN) ? p0.x : 0;
        int c1 = ((unsigned)p1.x < NN) ? p1.x : 0;
        float w0 = __int_as_float(p0.y);
        float w1 = __int_as_float(p1.y);
        float2 h0 = *(const float2*)&X[c0 * DD + c];
        float2 h1 = *(const float2*)&X[c1 * DD + c];
        acc.x = fmaf(h0.x, w0, acc.x);
        acc.y = fmaf(h0.y, w0, acc.y);
        acc.x = fmaf(h1.x, w1, acc.x);
        acc.y = fmaf(h1.y, w1, acc.y);
    }
    if (j < end) {
        int2 p0 = pairs[j];
        int c0 = ((unsigned)p0.x < NN) ? p0.x : 0;
        float w0 = __int_as_float(p0.y);
        float2 h0 = *(const float2*)&X[c0 * DD + c];
        acc.x = fmaf(h0.x, w0, acc.x);
        acc.y = fmaf(h0.y, w0, acc.y);
    }
    *(float2*)&G[node * DD + c] = acc;
}

// ---------------- CSR gather, bf16 source (layers 1-3; halves read traffic) ----------------
__global__ __launch_bounds__(256) void k_gather_bf(
        const unsigned short* __restrict__ H, const int* __restrict__ rowptr,
        const int2* __restrict__ pairs, float* __restrict__ G) {
    int node = blockIdx.x * 4 + (threadIdx.x >> 6);
    if (node >= NN) return;
    int lane = threadIdx.x & 63;
    int c = lane * 2;
    int j = rowptr[node];
    int end = rowptr[node + 1];
    j = max(0, min(j, EE));
    end = max(j, min(end, EE));
    float2 acc = make_float2(0.f, 0.f);
    for (; j + 1 < end; j += 2) {
        int2 p0 = pairs[j];
        int2 p1 = pairs[j + 1];
        int c0 = ((unsigned)p0.x < NN) ? p0.x : 0;
        int c1 = ((unsigned)p1.x < NN) ? p1.x : 0;
        float w0 = __int_as_float(p0.y);
        float w1 = __int_as_float(p1.y);
        ushort2 h0 = *(const ushort2*)&H[c0 * DD + c];
        ushort2 h1 = *(const ushort2*)&H[c1 * DD + c];
        acc.x = fmaf(bf2f(h0.x), w0, acc.x);
        acc.y = fmaf(bf2f(h0.y), w0, acc.y);
        acc.x = fmaf(bf2f(h1.x), w1, acc.x);
        acc.y = fmaf(bf2f(h1.y), w1, acc.y);
    }
    if (j < end) {
        int2 p0 = pairs[j];
        int c0 = ((unsigned)p0.x < NN) ? p0.x : 0;
        float w0 = __int_as_float(p0.y);
        ushort2 h0 = *(const ushort2*)&H[c0 * DD + c];
        acc.x = fmaf(bf2f(h0.x), w0, acc.x);
        acc.y = fmaf(bf2f(h0.y), w0, acc.y);
    }
    *(float2*)&G[node * DD + c] = acc;
}

// ---------------- W prep: fp32 [k][c] -> bf16 hi/lo, plain transposed layout [c][k] ----------------
__global__ __launch_bounds__(128) void k_prepw(
        const float* __restrict__ W1, const float* __restrict__ W2,
        const float* __restrict__ W3, const float* __restrict__ W4,
        const float* __restrict__ Wr,
        unsigned short* __restrict__ WH, unsigned short* __restrict__ WL) {
    int m = blockIdx.x >> 7;
    int c = blockIdx.x & 127;
    int k = threadIdx.x;
    const float* Wm = (m == 0) ? W1 : (m == 1) ? W2 : (m == 2) ? W3 : (m == 3) ? W4 : Wr;
    float x = Wm[k * 128 + c];
    unsigned short hi = f2bf(x);
    unsigned short lo = f2bf(x - bf2f(hi));
    int off = m * 16384 + c * 128 + k;
    WH[off] = hi;
    WL[off] = lo;
}

// ---------------- MFMA split-precision GEMM v4: W in registers, X-only LDS ----------------
// 512 threads / 8 waves; block = 64 rows x 128 cols; wave w owns cols [16w,16w+16).
// B-operand (16 cols x K=128, hi+lo) = 8 bf16x8 frags = 32 VGPR, loaded from global.
// acc += Ah*Bh + Ah*Bl + Al*Bh   (residual ~2^-17)
#define GTILE 64
__global__ __launch_bounds__(512) void k_gemm_mfma(
        const float* __restrict__ X,
        const unsigned short* __restrict__ Wh, const unsigned short* __restrict__ Wl,
        const float* __restrict__ bias, const float* __restrict__ RES,
        float* __restrict__ Yf, unsigned short* __restrict__ Yb, int M, int relu) {
    __shared__ unsigned short Xh[GTILE * 128];
    __shared__ unsigned short Xlo[GTILE * 128];

    const int t = threadIdx.x;
    const int row0 = blockIdx.x * GTILE;
    const float4* X4 = (const float4*)X;

    const int lane = t & 63;
    const int wav = t >> 6;
    const int lr = lane & 15;
    const int lk = lane >> 4;

    // ---- load W fragments into registers (L2-resident after first blocks) ----
    bf16x8 bh[4], bl[4];
    {
        const int c = 16 * wav + lr;
#pragma unroll
        for (int k0 = 0; k0 < 4; ++k0) {
            int off = c * 128 + k0 * 32 + lk * 8;
            bh[k0] = *(const bf16x8*)&Wh[off];
            bl[k0] = *(const bf16x8*)&Wl[off];
        }
    }

    // ---- stage X: fp32 -> hi/lo bf16, swizzled (4 float4 per thread) ----
    for (int i = t; i < GTILE * 32; i += 512) {
        int r = i >> 5;
        int c4 = i & 31;
        int gr = row0 + r;
        float4 v = make_float4(0.f, 0.f, 0.f, 0.f);
        if (gr < M) v = X4[(long long)gr * 32 + c4];
        ushort4 h, lo;
        h.x = f2bf(v.x); lo.x = f2bf(v.x - bf2f(h.x));
        h.y = f2bf(v.y); lo.y = f2bf(v.y - bf2f(h.y));
        h.z = f2bf(v.z); lo.z = f2bf(v.z - bf2f(h.z));
        h.w = f2bf(v.w); lo.w = f2bf(v.w - bf2f(h.w));
        int base = r * 128 + ((c4 * 4) ^ ((r & 7) << 3));
        *(ushort4*)&Xh[base] = h;
        *(ushort4*)&Xlo[base] = lo;
    }
    __syncthreads();

    f32x4 acc[4];
#pragma unroll
    for (int m = 0; m < 4; ++m) acc[m] = (f32x4){0.f, 0.f, 0.f, 0.f};

#pragma unroll
    for (int k0 = 0; k0 < 4; ++k0) {
        const int kbase = k0 * 32 + lk * 8;
        bf16x8 ah[4], al[4];
#pragma unroll
        for (int m = 0; m < 4; ++m) {
            int row = 16 * m + lr;
            int off = row * 128 + (kbase ^ ((row & 7) << 3));
            ah[m] = *(const bf16x8*)&Xh[off];
            al[m] = *(const bf16x8*)&Xlo[off];
        }
#pragma unroll
        for (int m = 0; m < 4; ++m) {
            acc[m] = __builtin_amdgcn_mfma_f32_16x16x32_bf16(ah[m], bh[k0], acc[m], 0, 0, 0);
            acc[m] = __builtin_amdgcn_mfma_f32_16x16x32_bf16(ah[m], bl[k0], acc[m], 0, 0, 0);
            acc[m] = __builtin_amdgcn_mfma_f32_16x16x32_bf16(al[m], bh[k0], acc[m], 0, 0, 0);
        }
    }

    // epilogue: C/D layout col = lane&15, row = (lane>>4)*4 + j
    {
        int gc = 16 * wav + lr;
        float bv = bias[gc];
#pragma unroll
        for (int m = 0; m < 4; ++m) {
#pragma unroll
            for (int j = 0; j < 4; ++j) {
                int gr = row0 + 16 * m + lk * 4 + j;
                if (gr < M) {
                    float a = acc[m][j] + bv;
                    if (RES) a += RES[(long long)gr * DD + gc];
                    if (relu) a = fmaxf(a, 0.f);
                    if (Yb) Yb[(long long)gr * DD + gc] = f2bf(a);
                    else    Yf[(long long)gr * DD + gc] = a;
                }
            }
        }
    }
}

// ---------------- final projection: out[M,16] = X[M,128] @ Wo[128,16] + bo ----------------
__global__ __launch_bounds__(256) void k_gemm_out(
        const float* __restrict__ X, const float* __restrict__ Wo,
        const float* __restrict__ bo, float* __restrict__ Y, int M) {
    __shared__ float Wlds[128 * 16];
    int t = threadIdx.x;
    for (int i = t * 4; i < 128 * 16; i += 256 * 4) {
        *(float4*)&Wlds[i] = *(const float4*)&Wo[i];
    }
    __syncthreads();
    int r = blockIdx.x * blockDim.x + t;
    if (r < M) {
        float acc[16];
#pragma unroll
        for (int j = 0; j < 16; ++j) acc[j] = bo[j];
#pragma unroll
        for (int k = 0; k < 128; k += 4) {
            float4 x = *(const float4*)&X[(long long)r * DD + k];
#pragma unroll
            for (int j = 0; j < 16; ++j) {
                acc[j] += x.x * Wlds[(k + 0) * 16 + j] + x.y * Wlds[(k + 1) * 16 + j]
                        + x.z * Wlds[(k + 2) * 16 + j] + x.w * Wlds[(k + 3) * 16 + j];
            }
        }
#pragma unroll
        for (int j = 0; j < 16; j += 4) {
            float4 o = make_float4(acc[j], acc[j + 1], acc[j + 2], acc[j + 3]);
            *(float4*)&Y[(long long)r * CC + j] = o;
        }
    }
}

extern "C" void kernel_launch(void* const* d_in, const int* in_sizes, int n_in,
                              void* d_out, int out_size, void* d_ws, size_t ws_size,
                              hipStream_t stream) {
    const int*   src = (const int*)d_in[0];
    const int*   dst = (const int*)d_in[1];
    const float* inputs = (const float*)d_in[2];
    const float* ew  = (const float*)d_in[3];
    const float* W1  = (const float*)d_in[4];
    const float* b1  = (const float*)d_in[5];
    const float* W2  = (const float*)d_in[6];
    const float* b2  = (const float*)d_in[7];
    const float* W3  = (const float*)d_in[8];
    const float* b3  = (const float*)d_in[9];
    const float* W4  = (const float*)d_in[10];
    const float* b4  = (const float*)d_in[11];
    const float* Wr  = (const float*)d_in[12];
    const float* br  = (const float*)d_in[13];
    const float* Wo  = (const float*)d_in[14];
    const float* bo  = (const float*)d_in[15];
    float* out = (float*)d_out;

    // workspace layout
    char* p = (char*)d_ws;
    float* iso    = (float*)p; p += sizeof(float) * NN;
    float* isi    = (float*)p; p += sizeof(float) * NN;
    int*   cs     = (int*)p;   p += sizeof(int) * NN;      // reused as WHg after fill
    int*   cd     = (int*)p;   p += sizeof(int) * NN;
    int*   cursor = (int*)p;   p += sizeof(int) * NN;
    int*   rowptr = (int*)p;   p += sizeof(int) * (NN + 1);
    int*   partial= (int*)p;   p += sizeof(int) * NBLK_SCAN;
    int*   pp     = (int*)p;   p += sizeof(int) * NBLK_SCAN;
    p = (char*)(((uintptr_t)p + 255) & ~(uintptr_t)255);
    int2*  pairs  = (int2*)p;  p += sizeof(int2) * EE;
    float* RES    = (float*)p; p += sizeof(float) * (size_t)NN * DD;
    float* G      = (float*)p; p += sizeof(float) * (size_t)NN * DD;
    float* X0     = (float*)p; p += sizeof(float) * (size_t)NN * DD;

    // aliases:
    unsigned short* WHg = (unsigned short*)cs;            // 160KB over cs + part of cd
    unsigned short* WLg = WHg + 5 * 16384;                // 160KB (ends before cursor)
    unsigned int*   hist = (unsigned int*)G;              // 64 copies x 50K packed = 12.8MB
    unsigned short* H   = (unsigned short*)X0;            // bf16 intermediate (12.8MB)

    const int GEMM_GRID = (NN + GTILE - 1) / GTILE;       // 782

    // ---- degrees via privatized histogram (on G region) ----
    hipMemsetAsync(hist, 0, sizeof(unsigned int) * (size_t)HCOPIES * NN, stream);
    hipMemsetAsync(cursor, 0, sizeof(int) * NN, stream);
    k_hist<<<(EE + 255) / 256, 256, 0, stream>>>(src, dst, hist);
    k_reduce_deg<<<(NN + 255) / 256, 256, 0, stream>>>(hist, cd, iso, isi);
    k_blocksum<<<NBLK_SCAN, SBLK, 0, stream>>>(cd, partial);
    k_scanpartial<<<1, SBLK, 0, stream>>>(partial, pp, rowptr);
    k_writerowptr<<<NBLK_SCAN, SBLK, 0, stream>>>(cd, pp, rowptr);
    k_fill<<<(EE + 255) / 256, 256, 0, stream>>>(src, dst, ew, iso, isi, rowptr, cursor, pairs);

    // ---- prep bf16 hi/lo weights (after fill: cs/cd dead) ----
    k_prepw<<<5 * 128, 128, 0, stream>>>(W1, W2, W3, W4, Wr, WHg, WLg);

    // ---- res = inputs @ Wr + br (fp32 out) ----
    k_gemm_mfma<<<GEMM_GRID, 512, 0, stream>>>(inputs, WHg + 4 * 16384, WLg + 4 * 16384,
                                               br, nullptr, RES, nullptr, NN, 0);

    const float* bs[4] = {b1, b2, b3, b4};
    for (int l = 0; l < 4; ++l) {
        if (l == 0)
            k_gather<<<(NN + 3) / 4, 256, 0, stream>>>(inputs, rowptr, pairs, G);
        else
            k_gather_bf<<<(NN + 3) / 4, 256, 0, stream>>>(H, rowptr, pairs, G);

        if (l < 3) {
            // bf16 output -> feeds next gather only
            k_gemm_mfma<<<GEMM_GRID, 512, 0, stream>>>(G, WHg + l * 16384, WLg + l * 16384,
                                                       bs[l], nullptr, nullptr, H, NN, 1);
        } else {
            // final conv layer: +RES, relu, fp32 out
            k_gemm_mfma<<<GEMM_GRID, 512, 0, stream>>>(G, WHg + l * 16384, WLg + l * 16384,
                                                       bs[l], RES, X0, nullptr, NN, 1);
        }
    }

    k_gemm_out<<<(NN + 255) / 256, 256, 0, stream>>>(X0, Wo, bo, out, NN);
}